// Round 19
// baseline (1003.797 us; speedup 1.0000x reference)
//
#include <hip/hip_runtime.h>
#include <math.h>

#define NA    360
#define ZPT   8
#define CROWS 24            // staged v-rows (24-row window proven R5-R18)
#define CPITCH 52           // cells per row (52-col u-window proven R5-R18)
#define NCELLP 1280         // padded cells per buffer (2560 dwords staged)
#define VLO_MAX 231         // padded staging row v_lo+24 stays in-slab
#define ULO_MAX 204         // ui <= 50 -> ui+1 tap <= 51 in 52-col row
#define BSTRIDE 94371840    // bytes per batch slab = 360*65536*4

// Cone-beam backprojection, batch-fused, interleaved {b0,b1} float2 cells,
// taps = 2x ds_read2_b64 per k. R19 change: sync structure only (T3/T4).
// R16/R18 diagnosis: VALU 46%, LDS ~45%, wall ~= sum -> the per-angle
// __syncthreads (vmcnt(0)+lgkmcnt(0) drain) serializes the two pipes and
// parks all waves on the staging round-trip each angle. Replace with:
// 4-buffer rotation, staging 3 angles ahead, s_waitcnt vmcnt(20) (counted:
// only angle a's 10 loads must land; 20 newer stay in flight) + RAW s_barrier
// (no drain). Hazards: between barrier(a) and barrier(a+1), reads hit
// buf[a&3], writes hit buf[(a+3)&3]=buf[(a-1)&3] (disjoint); stage(a+3) is
// issued post-barrier(a), after every wave's compute(a-1) reads (pre-barrier).
// Staging stays global_load_lds ONLY (R13: reg-staged scatter -> FETCH 16GB).
// ULO_MAX=204 load-bearing for the 52-col window (R15 lesson at 64-col).
// Geometry: dz=dy=dx=2mm, dv=du=2mm, DSO=1000, DSD=1536, mag in [1.302,1.872];
// iv in (8.6,246.4) -> v never clamps, v0+1 in-bounds; v0-vlo in [0,22].

typedef float v2f __attribute__((ext_vector_type(2)));
typedef __attribute__((address_space(1))) const void gas_t;
typedef __attribute__((address_space(3))) void las_t;

__device__ __forceinline__ int2 bbox_angle(float c, float s,
    float xclo, float xchi, float yclo, float ychi, float zvlo, float zvhi)
{
    const float a0 = xclo*c, a1 = xchi*c, b0 = yclo*s, b1 = ychi*s;
    const float xr0 = a0+b0, xr1 = a0+b1, xr2 = a1+b0, xr3 = a1+b1;
    const float xmn = fminf(fminf(xr0,xr1), fminf(xr2,xr3));
    const float xmx = fmaxf(fmaxf(xr0,xr1), fmaxf(xr2,xr3));
    const float c0 = yclo*c, c1 = ychi*c, d0 = xclo*s, d1 = xchi*s;
    const float yr0 = c0-d0, yr1 = c0-d1, yr2 = c1-d0, yr3 = c1-d1;
    const float ymn = fminf(fminf(yr0,yr1), fminf(yr2,yr3));
    const float ymx = fmaxf(fmaxf(yr0,yr1), fmaxf(yr2,yr3));
    const float mlo = 1536.f * __builtin_amdgcn_rcpf(1000.f - xmn);
    const float mhi = 1536.f * __builtin_amdgcn_rcpf(1000.f - xmx);
    const float umn = fminf(fminf(ymn*mlo, ymn*mhi), fminf(ymx*mlo, ymx*mhi));
    int u_lo = (int)floorf(fmaf(umn, 0.5f, 127.5f)) - 1;
    u_lo = u_lo < 0 ? 0 : (u_lo > ULO_MAX ? ULO_MAX : u_lo);
    const float vmn = fminf(fminf(zvlo*mlo, zvlo*mhi), fminf(zvhi*mlo, zvhi*mhi));
    int v_lo = (int)floorf(vmn + 127.5f) - 1;
    v_lo = v_lo < 0 ? 0 : (v_lo > VLO_MAX ? VLO_MAX : v_lo);
    return make_int2(u_lo, v_lo);
}

// Wave w stages buffer dwords [w*640 .. w*640+639] (10 width-4 gl_lds).
__device__ __forceinline__ void stage10(const char* gb, float* ldsw,
                                        const int goffB[10]) {
    #pragma unroll
    for (int i = 0; i < 10; ++i) {
        __builtin_amdgcn_global_load_lds(
            (gas_t*)(gb + goffB[i]),
            (las_t*)(ldsw + i * 64), 4, 0, 0);
    }
}

__device__ __forceinline__ void compute_angle(const v2f* __restrict__ smb,
    float c, float s, float xc, float yc, float zf0, int u_lo, int v_lo,
    v2f acc[ZPT])
{
    const float xr  = xc*c + yc*s;
    const float yr  = yc*c - xc*s;
    const float mag = 1536.f * __builtin_amdgcn_rcpf(1000.f - xr);
    const float iu  = fmaf(yr*mag, 0.5f, 127.5f);
    const bool uval = (iu >= 0.f) && (iu <= 255.f);
    const float iuc = fminf(fmaxf(iu, 0.f), 255.f);
    int u0 = (int)iuc; u0 = u0 > 254 ? 254 : u0;
    const float fu  = iuc - (float)u0;
    const float w   = uval ? 1.f : 0.f;
    const float wu1 = fu*w, wu0 = w - wu1;
    const v2f   w0v = {wu0, wu0};
    const v2f   w1v = {wu1, wu1};
    const int   ui  = u0 - u_lo;                         // <= 50 for valid taps
    const float ivb = fmaf(zf0, mag, 127.5f) - (float)v_lo;
    #pragma unroll
    for (int k = 0; k < ZPT; ++k) {
        const float ivl = fmaf((float)k, mag, ivb);
        const int   v0  = (int)ivl;                      // >0 -> trunc==floor
        const float fv  = __builtin_amdgcn_fractf(ivl);
        const v2f* cell = smb + (v0 * CPITCH + ui);
        const v2f c00 = cell[0];                         // {b0,b1}@(v0,  u0)
        const v2f c10 = cell[CPITCH];                    // (v0+1,u0)   read2_b64
        const v2f c01 = cell[1];                         // (v0,  u0+1)
        const v2f c11 = cell[CPITCH+1];                  // (v0+1,u0+1) read2_b64
        const v2f fvv = {fv, fv};
        const v2f q0 = __builtin_elementwise_fma(fvv, c10 - c00, c00);
        const v2f q1 = __builtin_elementwise_fma(fvv, c11 - c01, c01);
        acc[k] = __builtin_elementwise_fma(w0v, q0, acc[k]);
        acc[k] = __builtin_elementwise_fma(w1v, q1, acc[k]);
    }
}

__global__ __launch_bounds__(256, 3) void bp_kernel(const float* __restrict__ proj,
                                                    float* __restrict__ out) {
    __shared__ float2 cs_sh[NA];
    __shared__ int2   bb_sh[NA];
    __shared__ v2f    patch[4][NCELLP];   // 4-buffer rotation, 40.96 KB

    const int tid = threadIdx.y * 16 + threadIdx.x;

    const int zg = blockIdx.x;            // z-group (16)
    const int t  = blockIdx.y;            // xy tile (64)
    const int x0 = (t & 7) * 16;
    const int y0 = (t >> 3) * 16;
    const int zb = zg * ZPT;

    const float zf0  = (float)zb - 63.5f;
    const float xclo = ((float)x0 - 63.5f) * 2.f, xchi = xclo + 30.f;
    const float yclo = ((float)y0 - 63.5f) * 2.f, ychi = yclo + 30.f;

    for (int i = tid; i < NA; i += 256) {
        float th = (float)i * (float)(2.0 * M_PI / (double)NA);
        float sv, cv; sincosf(th, &sv, &cv);
        cs_sh[i] = make_float2(cv, sv);
        bb_sh[i] = bbox_angle(cv, sv, xclo, xchi, yclo, ychi, zf0, zf0 + 7.f);
    }
    __syncthreads();

    // per-lane staging source offsets (constant across angles):
    // buffer dword f = wv*640 + i*64 + lane -> batch=f&1, cell=f>>1,
    // v=cell/52, ucol=cell%52. Source = angle origin + batch*BSTRIDE
    // + v*1024 + ucol*4. Padded cells (>=1248) read row v_lo+24 (in-slab).
    const int wv   = tid >> 6;
    const int lane = tid & 63;
    int goffB[10];
    #pragma unroll
    for (int i = 0; i < 10; ++i) {
        const int f    = wv * 640 + i * 64 + lane;
        const int bsel = f & 1;
        const int cidx = f >> 1;
        const int v    = cidx / 52;           // init-only exact division
        const int ucol = cidx - v * 52;
        goffB[i] = bsel * BSTRIDE + v * 1024 + ucol * 4;
    }

    const char* projB = (const char*)proj;
    const float xc = ((float)(x0 + threadIdx.x) - 63.5f) * 2.f;
    const float yc = ((float)(y0 + threadIdx.y) - 63.5f) * 2.f;

    v2f acc[ZPT];
    #pragma unroll
    for (int k = 0; k < ZPT; ++k) acc[k] = (v2f){0.f, 0.f};

    // prologue: stage angles 0,1,2 into buffers 0,1,2 (30 loads in flight)
    #pragma unroll
    for (int p = 0; p < 3; ++p) {
        const int2 lo = bb_sh[p];
        const uint32_t aoff = __builtin_amdgcn_readfirstlane(
            (uint32_t)p * 262144u +
            ((uint32_t)lo.y << 10) + ((uint32_t)lo.x << 2));
        stage10(projB + aoff, (float*)&patch[p][0] + wv * 640, goffB);
    }

    for (int a = 0; a < NA; ++a) {
        // wait: angle a's 10 loads landed (a+1,a+2[,a+3 not yet] = 20 in flight)
        asm volatile("s_waitcnt vmcnt(20)" ::: "memory");
        __builtin_amdgcn_s_barrier();        // raw: no vmcnt/lgkmcnt drain

        {   // stage a+3 into buf[(a+3)&3] (wraps past 359: harmless re-stage)
            int an = a + 3; if (an >= NA) an -= NA;
            const int2 lo = bb_sh[an];
            const uint32_t aoff = __builtin_amdgcn_readfirstlane(
                (uint32_t)an * 262144u +
                ((uint32_t)lo.y << 10) + ((uint32_t)lo.x << 2));
            stage10(projB + aoff, (float*)&patch[(a + 3) & 3][0] + wv * 640, goffB);
        }
        {
            const float2 cs = cs_sh[a];
            const int2   lo = bb_sh[a];
            compute_angle(patch[a & 3], cs.x, cs.y, xc, yc, zf0, lo.x, lo.y, acc);
        }
    }

    // drain pending gl_lds DMA before workgroup LDS is released
    asm volatile("s_waitcnt vmcnt(0)" ::: "memory");

    float* o0 = out + (((size_t)zb) * 128 + (y0 + threadIdx.y)) * 128
                    + (x0 + threadIdx.x);
    float* o1 = o0 + (size_t)128 * 128 * 128;   // batch 1 volume
    #pragma unroll
    for (int k = 0; k < ZPT; ++k) {
        o0[(size_t)k * (128 * 128)] = acc[k].x;
        o1[(size_t)k * (128 * 128)] = acc[k].y;
    }
}

extern "C" void kernel_launch(void* const* d_in, const int* in_sizes, int n_in,
                              void* d_out, int out_size, void* d_ws, size_t ws_size,
                              hipStream_t stream) {
    const float* proj = (const float*)d_in[0];
    float* out = (float*)d_out;
    dim3 grid(128 / ZPT, 64, 1);   // (z-groups, xy-tiles) = 1024 blocks, batch fused
    dim3 block(16, 16, 1);
    hipLaunchKernelGGL(bp_kernel, grid, block, 0, stream, proj, out);
}

// Round 20
// 812.070 us; speedup vs baseline: 1.2361x; 1.2361x over previous
//
#include <hip/hip_runtime.h>
#include <math.h>

#define NA    360
#define ZPT   8
#define CROWS 24            // staged v-rows (24-row window proven R5-R18)
#define CPITCH 52           // cells per row (52-col u-window proven R5-R18)
#define NCELLP 1280         // padded cells per buffer (2560 dwords staged)
#define VLO_MAX 231         // padded staging row v_lo+24 stays in-slab
#define ULO_MAX 204         // ui <= 50 -> ui+1 tap <= 51 in 52-col row
#define BSTRIDE 94371840    // bytes per batch slab = 360*65536*4

// Cone-beam backprojection, batch-fused, interleaved {b0,b1} float2 cells,
// taps = 2x ds_read2_b64 per k. R20: R19's counted-vmcnt/raw-barrier pipeline
// retested at ISO-OCCUPANCY (R19 conflated it with a 4->3 blocks/CU drop:
// 47KB LDS). 3-buffer rotation, stage depth 2, s_waitcnt vmcnt(10); LDS =
// 3*10.24KB + 360*16B = 36.5KB -> 4 blocks/CU like R16. Hazards: interval a
// reads buf[a%3], writes buf[(a+2)%3] (disjoint); interval-(a-1) ds_reads are
// a full compute phase older than interval-a DMA arrivals (R19 verified,
// absmax 0.25). Staging stays global_load_lds ONLY (R13 lesson).
// Geometry: dz=dy=dx=2mm, dv=du=2mm, DSO=1000, DSD=1536, mag in [1.302,1.872];
// iv in (8.6,246.4) -> v never clamps, v0+1 in-bounds; v0-vlo in [0,22].

typedef float v2f __attribute__((ext_vector_type(2)));
typedef __attribute__((address_space(1))) const void gas_t;
typedef __attribute__((address_space(3))) void las_t;

struct __align__(16) Ang { float c, s; int ulo, vlo; };

__device__ __forceinline__ Ang ang_setup(int i, float xclo, float xchi,
                                         float yclo, float ychi,
                                         float zvlo, float zvhi)
{
    float th = (float)i * (float)(2.0 * M_PI / (double)NA);
    float s, c; sincosf(th, &s, &c);
    const float a0 = xclo*c, a1 = xchi*c, b0 = yclo*s, b1 = ychi*s;
    const float xr0 = a0+b0, xr1 = a0+b1, xr2 = a1+b0, xr3 = a1+b1;
    const float xmn = fminf(fminf(xr0,xr1), fminf(xr2,xr3));
    const float xmx = fmaxf(fmaxf(xr0,xr1), fmaxf(xr2,xr3));
    const float c0 = yclo*c, c1 = ychi*c, d0 = xclo*s, d1 = xchi*s;
    const float yr0 = c0-d0, yr1 = c0-d1, yr2 = c1-d0, yr3 = c1-d1;
    const float ymn = fminf(fminf(yr0,yr1), fminf(yr2,yr3));
    const float ymx = fmaxf(fmaxf(yr0,yr1), fmaxf(yr2,yr3));
    const float mlo = 1536.f * __builtin_amdgcn_rcpf(1000.f - xmn);
    const float mhi = 1536.f * __builtin_amdgcn_rcpf(1000.f - xmx);
    const float umn = fminf(fminf(ymn*mlo, ymn*mhi), fminf(ymx*mlo, ymx*mhi));
    int u_lo = (int)floorf(fmaf(umn, 0.5f, 127.5f)) - 1;
    u_lo = u_lo < 0 ? 0 : (u_lo > ULO_MAX ? ULO_MAX : u_lo);
    const float vmn = fminf(fminf(zvlo*mlo, zvlo*mhi), fminf(zvhi*mlo, zvhi*mhi));
    int v_lo = (int)floorf(vmn + 127.5f) - 1;
    v_lo = v_lo < 0 ? 0 : (v_lo > VLO_MAX ? VLO_MAX : v_lo);
    Ang g; g.c = c; g.s = s; g.ulo = u_lo; g.vlo = v_lo;
    return g;
}

// Wave w stages buffer dwords [w*640 .. w*640+639] (10 width-4 gl_lds).
__device__ __forceinline__ void stage10(const char* gb, float* ldsw,
                                        const int goffB[10]) {
    #pragma unroll
    for (int i = 0; i < 10; ++i) {
        __builtin_amdgcn_global_load_lds(
            (gas_t*)(gb + goffB[i]),
            (las_t*)(ldsw + i * 64), 4, 0, 0);
    }
}

__device__ __forceinline__ void compute_angle(const v2f* __restrict__ smb,
    const Ang g, float xc, float yc, float zf0, v2f acc[ZPT])
{
    const float xr  = xc*g.c + yc*g.s;
    const float yr  = yc*g.c - xc*g.s;
    const float mag = 1536.f * __builtin_amdgcn_rcpf(1000.f - xr);
    const float iu  = fmaf(yr*mag, 0.5f, 127.5f);
    const bool uval = (iu >= 0.f) && (iu <= 255.f);
    const float iuc = fminf(fmaxf(iu, 0.f), 255.f);
    int u0 = (int)iuc; u0 = u0 > 254 ? 254 : u0;
    const float fu  = iuc - (float)u0;
    const float w   = uval ? 1.f : 0.f;
    const float wu1 = fu*w, wu0 = w - wu1;
    const v2f   w0v = {wu0, wu0};
    const v2f   w1v = {wu1, wu1};
    const int   ui  = u0 - g.ulo;                        // <= 50 for valid taps
    const float ivb = fmaf(zf0, mag, 127.5f) - (float)g.vlo;
    #pragma unroll
    for (int k = 0; k < ZPT; ++k) {
        const float ivl = fmaf((float)k, mag, ivb);
        const int   v0  = (int)ivl;                      // >0 -> trunc==floor
        const float fv  = __builtin_amdgcn_fractf(ivl);
        const v2f* cell = smb + (v0 * CPITCH + ui);
        const v2f c00 = cell[0];                         // {b0,b1}@(v0,  u0)
        const v2f c10 = cell[CPITCH];                    // (v0+1,u0)   read2_b64
        const v2f c01 = cell[1];                         // (v0,  u0+1)
        const v2f c11 = cell[CPITCH+1];                  // (v0+1,u0+1) read2_b64
        const v2f fvv = {fv, fv};
        const v2f q0 = __builtin_elementwise_fma(fvv, c10 - c00, c00);
        const v2f q1 = __builtin_elementwise_fma(fvv, c11 - c01, c01);
        acc[k] = __builtin_elementwise_fma(w0v, q0, acc[k]);
        acc[k] = __builtin_elementwise_fma(w1v, q1, acc[k]);
    }
}

__global__ __launch_bounds__(256, 4) void bp_kernel(const float* __restrict__ proj,
                                                    float* __restrict__ out) {
    __shared__ Ang ang_sh[NA];
    __shared__ v2f patch[3][NCELLP];   // 3-buffer rotation, 30.7 KB

    const int tid = threadIdx.y * 16 + threadIdx.x;

    const int zg = blockIdx.x;            // z-group (16)
    const int t  = blockIdx.y;            // xy tile (64)
    const int x0 = (t & 7) * 16;
    const int y0 = (t >> 3) * 16;
    const int zb = zg * ZPT;

    const float zf0  = (float)zb - 63.5f;
    const float xclo = ((float)x0 - 63.5f) * 2.f, xchi = xclo + 30.f;
    const float yclo = ((float)y0 - 63.5f) * 2.f, ychi = yclo + 30.f;

    for (int i = tid; i < NA; i += 256)
        ang_sh[i] = ang_setup(i, xclo, xchi, yclo, ychi, zf0, zf0 + 7.f);
    __syncthreads();

    // per-lane staging source offsets (constant across angles):
    // buffer dword f = wv*640 + i*64 + lane -> batch=f&1, cell=f>>1,
    // v=cell/52, ucol=cell%52. Source = angle origin + batch*BSTRIDE
    // + v*1024 + ucol*4. Padded cells (>=1248) read row v_lo+24 (in-slab).
    const int wv   = tid >> 6;
    const int lane = tid & 63;
    int goffB[10];
    #pragma unroll
    for (int i = 0; i < 10; ++i) {
        const int f    = wv * 640 + i * 64 + lane;
        const int bsel = f & 1;
        const int cidx = f >> 1;
        const int v    = cidx / 52;           // init-only exact division
        const int ucol = cidx - v * 52;
        goffB[i] = bsel * BSTRIDE + v * 1024 + ucol * 4;
    }

    const char* projB = (const char*)proj;
    const float xc = ((float)(x0 + threadIdx.x) - 63.5f) * 2.f;
    const float yc = ((float)(y0 + threadIdx.y) - 63.5f) * 2.f;

    v2f acc[ZPT];
    #pragma unroll
    for (int k = 0; k < ZPT; ++k) acc[k] = (v2f){0.f, 0.f};

    // prologue: stage angles 0,1 into buffers 0,1 (20 loads in flight)
    #pragma unroll
    for (int p = 0; p < 2; ++p) {
        const Ang g = ang_sh[p];
        const uint32_t aoff = __builtin_amdgcn_readfirstlane(
            (uint32_t)p * 262144u +
            ((uint32_t)g.vlo << 10) + ((uint32_t)g.ulo << 2));
        stage10(projB + aoff, (float*)&patch[p][0] + wv * 640, goffB);
    }

    int bufc = 0, bufn = 2;   // compute buffer = a%3, stage buffer = (a+2)%3
    for (int a = 0; a < NA; ++a) {
        // wait: angle a's 10 loads landed (only a+1's 10 may remain in flight)
        asm volatile("s_waitcnt vmcnt(10)" ::: "memory");
        __builtin_amdgcn_s_barrier();        // raw: no vmcnt/lgkmcnt drain

        {   // stage a+2 into buf[(a+2)%3] (wraps past 359: harmless re-stage)
            int an = a + 2; if (an >= NA) an -= NA;
            const Ang g = ang_sh[an];
            const uint32_t aoff = __builtin_amdgcn_readfirstlane(
                (uint32_t)an * 262144u +
                ((uint32_t)g.vlo << 10) + ((uint32_t)g.ulo << 2));
            stage10(projB + aoff, (float*)&patch[bufn][0] + wv * 640, goffB);
        }
        compute_angle(patch[bufc], ang_sh[a], xc, yc, zf0, acc);

        bufc = bufc == 2 ? 0 : bufc + 1;
        bufn = bufn == 2 ? 0 : bufn + 1;
    }

    // drain pending gl_lds DMA before workgroup LDS is released
    asm volatile("s_waitcnt vmcnt(0)" ::: "memory");

    float* o0 = out + (((size_t)zb) * 128 + (y0 + threadIdx.y)) * 128
                    + (x0 + threadIdx.x);
    float* o1 = o0 + (size_t)128 * 128 * 128;   // batch 1 volume
    #pragma unroll
    for (int k = 0; k < ZPT; ++k) {
        o0[(size_t)k * (128 * 128)] = acc[k].x;
        o1[(size_t)k * (128 * 128)] = acc[k].y;
    }
}

extern "C" void kernel_launch(void* const* d_in, const int* in_sizes, int n_in,
                              void* d_out, int out_size, void* d_ws, size_t ws_size,
                              hipStream_t stream) {
    const float* proj = (const float*)d_in[0];
    float* out = (float*)d_out;
    dim3 grid(128 / ZPT, 64, 1);   // (z-groups, xy-tiles) = 1024 blocks, batch fused
    dim3 block(16, 16, 1);
    hipLaunchKernelGGL(bp_kernel, grid, block, 0, stream, proj, out);
}